// Round 5
// baseline (23.718 us; speedup 1.0000x reference)
//
#include <hip/hip_runtime.h>

// KAConv: out[b,f,h,w] = sum_{c,p} P_fcp(v) / (1 + |Q_fcp(v)|),
//   v = x[b,c,h+i-1,w+j-1] (zero pad), p = i*3+j
// Shapes: x[4,16,64,64], A[16,16,9,6], Bc[16,16,9,4], out[4,16,64,64], f32.
//
// Round 5 (one change vs round 4): stage the x-tile in LDS with zero-padded
// halo. Kills the 12 bounds-checked global loads per c-iteration (~50 VALU
// of overhead + exposed L1/L2 latency every iteration in every wave) and
// replaces them with 12 conflict-free stride-1 ds_read_b32.

#define BB   4
#define CIN  16
#define COUT 16
#define HH   64
#define WW   64

#define TROWS 10          // 8 output rows + 2 halo
#define TCOLS 66          // 64 cols + 2 halo
#define TSTR  68          // padded col stride
#define TCH   8           // channels per team

__global__ __launch_bounds__(512, 4) void KAConv_kernel(
    const float* __restrict__ x,    // [B,C,H,W]
    const float* __restrict__ A,    // [F,C,9,6]
    const float* __restrict__ Bc,   // [F,C,9,4]
    float* __restrict__ out)        // [B,F,H,W]
{
    // grid = b(4) x rowtile(8) x f(16) = 512 blocks; block = 512 = 8 waves,
    // 2 teams x 256 threads; team t handles channels t*8..t*8+7.
    const int blk   = blockIdx.x;
    const int f     = blk & 15;
    const int rtile = (blk >> 4) & 7;
    const int b     = blk >> 7;

    const int tid  = threadIdx.x;
    const int team = __builtin_amdgcn_readfirstlane(tid >> 8);   // 0 or 1
    const int tp   = tid & 255;
    const int w    = tp & 63;
    const int lr0  = (tp >> 6) << 1;              // tile-row of first pixel
    const int r0   = (rtile << 3) + lr0;          // global rows r0, r0+1
    const int c0   = team << 3;

    const float* __restrict__ xb = x  + (b * CIN + c0) * (HH * WW);
    const float* __restrict__ Af = A  + (f * CIN + c0) * 54;
    const float* __restrict__ Bf = Bc + (f * CIN + c0) * 36;

    __shared__ float tile[2][TCH][TROWS][TSTR];   // 43.5 KB
    __shared__ float sRed[2 * 256];               // 2 KB

    // ---- Stage 8 channels x 10 rows x 66 cols, zero-padded halo ----
    {
        const int r_lo = (rtile << 3) - 1;        // first staged global row
        for (int i = tp; i < TCH * TROWS * TCOLS; i += 256) {
            const int c   = i / (TROWS * TCOLS);
            const int rem = i - c * (TROWS * TCOLS);
            const int row = rem / TCOLS;
            const int col = rem - row * TCOLS;
            const int gh  = r_lo + row;
            const int gw  = col - 1;
            const bool ok = (gh >= 0) & (gh < HH) & (gw >= 0) & (gw < WW);
            tile[team][c][row][col] = ok ? xb[c * (HH * WW) + gh * WW + gw] : 0.0f;
        }
    }
    __syncthreads();

    float acc0 = 0.0f, acc1 = 0.0f;

    const float* __restrict__ tbase = &tile[team][0][0][0];

    #pragma unroll 2
    for (int c = 0; c < TCH; ++c) {
        const float* __restrict__ tc = tbase + c * (TROWS * TSTR);

        // 4 window rows x 3 col offsets from LDS (stride-1 -> conflict-free)
        float vv[4][3];
        #pragma unroll
        for (int ri = 0; ri < 4; ++ri)
            #pragma unroll
            for (int j = 0; j < 3; ++j)
                vv[ri][j] = tc[(lr0 + ri) * TSTR + (w + j)];

        const float* __restrict__ Ac = Af + c * 54;   // uniform -> s_load
        const float* __restrict__ Bq = Bf + c * 36;

        #pragma unroll
        for (int p = 0; p < 9; ++p) {
            const int i = p / 3;
            const int j = p % 3;
            const float va = vv[i][j];
            const float vb = vv[i + 1][j];
            const float* __restrict__ a  = Ac + p * 6;
            const float* __restrict__ bq = Bq + p * 4;

            float P0 = a[5], P1 = a[5];
            P0 = fmaf(P0, va, a[4]);  P1 = fmaf(P1, vb, a[4]);
            P0 = fmaf(P0, va, a[3]);  P1 = fmaf(P1, vb, a[3]);
            P0 = fmaf(P0, va, a[2]);  P1 = fmaf(P1, vb, a[2]);
            P0 = fmaf(P0, va, a[1]);  P1 = fmaf(P1, vb, a[1]);
            P0 = fmaf(P0, va, a[0]);  P1 = fmaf(P1, vb, a[0]);

            float q0 = bq[3], q1 = bq[3];
            q0 = fmaf(q0, va, bq[2]); q1 = fmaf(q1, vb, bq[2]);
            q0 = fmaf(q0, va, bq[1]); q1 = fmaf(q1, vb, bq[1]);
            q0 = fmaf(q0, va, bq[0]); q1 = fmaf(q1, vb, bq[0]);
            q0 *= va;                 q1 *= vb;

            const float d0 = 1.0f + fabsf(q0);
            const float d1 = 1.0f + fabsf(q1);
            acc0 = fmaf(P0, __builtin_amdgcn_rcpf(d0), acc0);
            acc1 = fmaf(P1, __builtin_amdgcn_rcpf(d1), acc1);
        }
    }

    // Reduce the two channel-halves: team 1 -> LDS, team 0 adds and stores.
    if (team == 1) {
        sRed[tp]       = acc0;
        sRed[256 + tp] = acc1;
    }
    __syncthreads();
    if (team == 0) {
        acc0 += sRed[tp];
        acc1 += sRed[256 + tp];
        float* __restrict__ of = out + ((b * COUT + f) * HH) * WW + w;
        of[r0 * WW]       = acc0;
        of[(r0 + 1) * WW] = acc1;
    }
}

extern "C" void kernel_launch(void* const* d_in, const int* in_sizes, int n_in,
                              void* d_out, int out_size, void* d_ws, size_t ws_size,
                              hipStream_t stream) {
    const float* x  = (const float*)d_in[0];
    const float* A  = (const float*)d_in[1];
    const float* Bc = (const float*)d_in[2];
    float* out = (float*)d_out;

    const int grid = BB * (HH / 8) * COUT;   // 512 blocks
    KAConv_kernel<<<grid, 512, 0, stream>>>(x, A, Bc, out);
}